// Round 3
// baseline (298.939 us; speedup 1.0000x reference)
//
#include <hip/hip_runtime.h>

#define BB 8
#define CC 128
#define NN 4096   // H*W = 64*64

typedef __bf16 bf16x8_t __attribute__((ext_vector_type(8)));
typedef unsigned short u16x8 __attribute__((ext_vector_type(8)));
typedef unsigned short u16x4 __attribute__((ext_vector_type(4)));
typedef float f32x4 __attribute__((ext_vector_type(4)));

__device__ __forceinline__ unsigned short f2bf(float f) {
  unsigned int u = __builtin_bit_cast(unsigned int, f);
  u += 0x7fffu + ((u >> 16) & 1u);          // RNE
  return (unsigned short)(u >> 16);
}

__device__ __forceinline__ f32x4 mfma_bf16(u16x8 a, u16x8 b, f32x4 c) {
  return __builtin_amdgcn_mfma_f32_16x16x32_bf16(
      __builtin_bit_cast(bf16x8_t, a), __builtin_bit_cast(bf16x8_t, b), c, 0, 0, 0);
}

// load 8 consecutive fp32 -> bf16x8 fragment
__device__ __forceinline__ u16x8 ldw8(const float* __restrict__ p) {
  float4 w0 = *(const float4*)p;
  float4 w1 = *(const float4*)(p + 4);
  u16x8 r;
  r[0] = f2bf(w0.x); r[1] = f2bf(w0.y); r[2] = f2bf(w0.z); r[3] = f2bf(w0.w);
  r[4] = f2bf(w1.x); r[5] = f2bf(w1.y); r[6] = f2bf(w1.z); r[7] = f2bf(w1.w);
  return r;
}

// ---------------------------------------------------------------------------
// Kernel 0: column sums of Wk.  csk[c] = sum_o Wk[o][c]
// (reference's einsum 'oc,bcn->bcn' contracts ONLY o; c is elementwise)
// ---------------------------------------------------------------------------
__global__ void colsum_k(const float* __restrict__ Wk, float* __restrict__ csk) {
  const int c = threadIdx.x;       // 128 threads
  float s = 0.f;
  for (int o = 0; o < CC; ++o) s += Wk[(size_t)o * CC + c];
  csk[c] = s;
}

// ---------------------------------------------------------------------------
// Kernel 1: QKV projection.  Per block: one batch b, 64 pixels.
//  Q[b][n][o] = (Σ_c Wq[o][c]·x[c][n] + bq[o]) * scale * log2e   (bf16, pixel-major)
//  K[b][n][c] =  x[c][n]·csk[c] + bk[c]                          (bf16, pixel-major)
//  V[b][o][n] =  Σ_c Wv[o][c]·x[c][n] + bv[o]                    (bf16, channel-major)
// ---------------------------------------------------------------------------
__global__ __launch_bounds__(256, 2) void qkv_proj(
    const float* __restrict__ x,
    const float* __restrict__ Wq, const float* __restrict__ bq,
    const float* __restrict__ csk, const float* __restrict__ bk,
    const float* __restrict__ Wv, const float* __restrict__ bv,
    unsigned short* __restrict__ Q,
    unsigned short* __restrict__ K,
    unsigned short* __restrict__ V)
{
  const int b  = blockIdx.x >> 6;
  const int n0 = (blockIdx.x & 63) << 6;
  const int t  = threadIdx.x;
  const int lane = t & 63;
  const int w  = t >> 6;        // wave 0..3, owns 16 pixel rows
  const int lq = lane & 15;
  const int g  = lane >> 4;

  __shared__ unsigned short xs[64][136];   // [n][c] bf16 x
  __shared__ unsigned short ks[64][136];   // [n][c] bf16 k
  __shared__ unsigned short vs[128][72];   // V^T staging [c][n]

  // stage x tile -> bf16 LDS (transposed to [n][c]); build K in the same pass
  {
    const int n = t & 63;                  // lane = pixel (coalesced over n)
    const float* xp = x + (size_t)b * (CC * NN) + n0 + n;
    for (int c = t >> 6; c < CC; c += 4) { // c is wave-uniform
      const float xv = xp[(size_t)c * NN];
      const float cs = csk[c], bb_ = bk[c];
      xs[n][c] = f2bf(xv);
      ks[n][c] = f2bf(xv * cs + bb_);
    }
  }
  __syncthreads();

  // A fragments: A[row=n][k=c], row = lane&15 within this wave's 16 rows
  u16x8 a[4];
  {
    const unsigned short* ap = &xs[w * 16 + lq][g * 8];
    for (int ksl = 0; ksl < 4; ++ksl) a[ksl] = *(const u16x8*)(ap + ksl * 32);
  }

  const float kscale = 0.08838834764831845f * 1.4426950408889634f; // 1/sqrt(C)*log2(e)

  for (int ot = 0; ot < 8; ++ot) {
    f32x4 aq = {0.f,0.f,0.f,0.f}, av = {0.f,0.f,0.f,0.f};
    const int o = ot * 16 + lq;            // B-frag col = output channel
    const float* wq = Wq + (size_t)o * CC + g * 8;
    const float* wv = Wv + (size_t)o * CC + g * 8;
    for (int ksl = 0; ksl < 4; ++ksl) {
      aq = mfma_bf16(a[ksl], ldw8(wq + ksl * 32), aq);
      av = mfma_bf16(a[ksl], ldw8(wv + ksl * 32), av);
    }
    const float bqv = bq[o], bvv = bv[o];
    for (int r = 0; r < 4; ++r) {
      const int nl = w * 16 + g * 4 + r;   // D row = local pixel
      const size_t base = ((size_t)b * NN + n0 + nl) * CC + o;
      Q[base] = f2bf((aq[r] + bqv) * kscale);
      vs[o][nl] = f2bf(av[r] + bvv);
    }
  }
  __syncthreads();

  // write K pixel-major, coalesced 16B
  {
    unsigned short* kout = K + ((size_t)b * NN + n0) * CC;
    for (int i = t; i < 64 * 16; i += 256) {
      const int n = i >> 4, oc = (i & 15) * 8;
      *(uint4*)(kout + (size_t)n * CC + oc) = *(const uint4*)&ks[n][oc];
    }
  }
  // write V channel-major, coalesced, 4B per store
  {
    unsigned short* vout = V + (size_t)b * (CC * NN) + n0;
    for (int i = t; i < 128 * 32; i += 256) {
      const int c  = i >> 5;
      const int np = (i & 31) << 1;
      *(unsigned int*)(vout + (size_t)c * NN + np) = *(const unsigned int*)&vs[c][np];
    }
  }
}

// ---------------------------------------------------------------------------
// Kernel 2: flash attention + residual.
// Block: batch b, 64 q-rows (4 waves x 16). KV tiles of 64.
// S^T = mfma(K, Q)  -> lane holds 16 scores of ONE q-column (q = lane&15)
// PV  = mfma(V^T, P^T) -> acc column = q = lane&15 (stats stay lane-local)
// D rows of PV acc = output channel -> direct channel-major store + residual.
// ---------------------------------------------------------------------------
__global__ __launch_bounds__(256, 2) void flash_attn(
    const float* __restrict__ x,
    const unsigned short* __restrict__ Q,
    const unsigned short* __restrict__ K,
    const unsigned short* __restrict__ V,
    float* __restrict__ out)
{
  const int b  = blockIdx.x >> 6;
  const int q0 = (blockIdx.x & 63) << 6;
  const int t  = threadIdx.x;
  const int lane = t & 63;
  const int w  = t >> 6;
  const int lq = lane & 15;
  const int g  = lane >> 4;

  __shared__ unsigned short Kt[64][136];     // [key][c]
  __shared__ unsigned short Vl[128][72];     // [c][key]  (V^T)
  __shared__ unsigned short Pt[4][16][72];   // per-wave [q][key]

  // Q fragments (B-operand of swapped QK^T): col q = lane&15
  u16x8 qf[4];
  {
    const unsigned short* qp = Q + ((size_t)b * NN + q0 + w * 16 + lq) * CC + g * 8;
    for (int ks = 0; ks < 4; ++ks) qf[ks] = *(const u16x8*)(qp + ks * 32);
  }

  f32x4 oacc[8];
  for (int i = 0; i < 8; ++i) oacc[i] = f32x4{0.f, 0.f, 0.f, 0.f};
  float m_run = -1e30f, l_run = 0.f;

  const uint4* ksrc = (const uint4*)(K + (size_t)b * NN * CC);
  const unsigned short* vsrc = V + (size_t)b * (CC * NN);

  for (int kv = 0; kv < NN; kv += 64) {
    __syncthreads();
    // ---- stage K tile: contiguous 16 KB ----
    {
      const uint4* src = ksrc + (size_t)kv * (CC / 8);
      for (int i = 0; i < 4; ++i) {
        const int idx = t + 256 * i;                  // 1024 x 16B
        uint4 val = src[idx];
        *(uint4*)&Kt[idx >> 4][(idx & 15) * 8] = val;
      }
    }
    // ---- stage V^T tile: 128 rows x 64 keys ----
    for (int i = 0; i < 4; ++i) {
      const int idx = t + 256 * i;                    // 1024 x 16B
      const int c = idx >> 3, col = (idx & 7) * 8;
      uint4 val = *(const uint4*)(vsrc + (size_t)c * NN + kv + col);
      *(uint4*)&Vl[c][col] = val;
    }
    __syncthreads();

    // ---- S^T = K . Q^T  (row = key, col = q) ----
    f32x4 s[4];
    for (int kt = 0; kt < 4; ++kt) s[kt] = f32x4{0.f, 0.f, 0.f, 0.f};
    for (int kt = 0; kt < 4; ++kt) {
      const unsigned short* kp = &Kt[kt * 16 + lq][g * 8];
      for (int ks = 0; ks < 4; ++ks) {
        u16x8 kf = *(const u16x8*)(kp + ks * 32);
        s[kt] = mfma_bf16(kf, qf[ks], s[kt]);
      }
    }

    // ---- online softmax over this 64-key tile (per q column) ----
    float pm = s[0][0];
    for (int kt = 0; kt < 4; ++kt)
      for (int r = 0; r < 4; ++r) pm = fmaxf(pm, s[kt][r]);
    pm = fmaxf(pm, __shfl_xor(pm, 16));
    pm = fmaxf(pm, __shfl_xor(pm, 32));
    const float m_new = fmaxf(m_run, pm);
    const float alpha = exp2f(m_run - m_new);
    float lsum = 0.f;
    for (int kt = 0; kt < 4; ++kt) {
      float p0 = exp2f(s[kt][0] - m_new), p1 = exp2f(s[kt][1] - m_new);
      float p2 = exp2f(s[kt][2] - m_new), p3 = exp2f(s[kt][3] - m_new);
      lsum += (p0 + p1) + (p2 + p3);
      u16x4 pk = { f2bf(p0), f2bf(p1), f2bf(p2), f2bf(p3) };
      *(u16x4*)&Pt[w][lq][kt * 16 + g * 4] = pk;     // keys kt*16 + g*4 + r
    }
    lsum += __shfl_xor(lsum, 16);
    lsum += __shfl_xor(lsum, 32);
    l_run = l_run * alpha + lsum;
    m_run = m_new;
    for (int i = 0; i < 8; ++i) {
      oacc[i][0] *= alpha; oacc[i][1] *= alpha;
      oacc[i][2] *= alpha; oacc[i][3] *= alpha;
    }
    // ensure the per-wave Pt writes are complete & not reordered vs reads
    asm volatile("s_waitcnt lgkmcnt(0)" ::: "memory");

    // ---- O^T += V^T . P^T  (row = channel, col = q) ----
    for (int kk = 0; kk < 2; ++kk) {
      u16x8 pf = *(const u16x8*)&Pt[w][lq][kk * 32 + g * 8];
      const unsigned short* vp = &Vl[lq][kk * 32 + g * 8];
      for (int dt = 0; dt < 8; ++dt) {
        u16x8 vf = *(const u16x8*)(vp + dt * 16 * 72);
        oacc[dt] = mfma_bf16(vf, pf, oacc[dt]);
      }
    }
  }

  // ---- epilogue: normalize, residual, channel-major store ----
  const float rinv = 1.0f / l_run;
  const int n = q0 + w * 16 + lq;
  for (int dt = 0; dt < 8; ++dt) {
    for (int r = 0; r < 4; ++r) {
      const int c = dt * 16 + g * 4 + r;
      const size_t adr = (size_t)b * (CC * NN) + (size_t)c * NN + n;
      out[adr] = x[adr] + oacc[dt][r] * rinv;
    }
  }
}

extern "C" void kernel_launch(void* const* d_in, const int* in_sizes, int n_in,
                              void* d_out, int out_size, void* d_ws, size_t ws_size,
                              hipStream_t stream) {
  (void)in_sizes; (void)n_in; (void)out_size; (void)ws_size;
  const float* x  = (const float*)d_in[0];
  const float* Wq = (const float*)d_in[1];
  const float* bq = (const float*)d_in[2];
  const float* Wk = (const float*)d_in[3];
  const float* bk = (const float*)d_in[4];
  const float* Wv = (const float*)d_in[5];
  const float* bv = (const float*)d_in[6];

  unsigned short* Q = (unsigned short*)d_ws;                 //  8 MB bf16 [B][N][C]
  unsigned short* K = Q + (size_t)BB * NN * CC;              //  8 MB bf16 [B][N][C]
  unsigned short* V = K + (size_t)BB * NN * CC;              //  8 MB bf16 [B][C][N]
  float* csk = (float*)(V + (size_t)BB * NN * CC);           //  512 B
  float* out = (float*)d_out;

  colsum_k<<<dim3(1), dim3(CC), 0, stream>>>(Wk, csk);
  qkv_proj<<<dim3(BB * (NN / 64)), dim3(256), 0, stream>>>(x, Wq, bq, csk, bk, Wv, bv, Q, K, V);
  flash_attn<<<dim3(BB * (NN / 64)), dim3(256), 0, stream>>>(x, Q, K, V, out);
}

// Round 4
// 147.092 us; speedup vs baseline: 2.0323x; 2.0323x over previous
//
#include <hip/hip_runtime.h>

#define BB 8
#define CC 128
#define NN 4096   // H*W = 64*64

typedef __bf16 bf16x8_t __attribute__((ext_vector_type(8)));
typedef unsigned short u16x8 __attribute__((ext_vector_type(8)));
typedef float f32x4 __attribute__((ext_vector_type(4)));
typedef __attribute__((address_space(1))) const unsigned int gu32;
typedef __attribute__((address_space(3))) unsigned int lu32;

#define KSCALE 0.12753262456033348f   // (1/sqrt(128)) * log2(e)

__device__ __forceinline__ unsigned short f2bf(float f) {
  unsigned int u = __builtin_bit_cast(unsigned int, f);
  u += 0x7fffu + ((u >> 16) & 1u);          // RNE
  return (unsigned short)(u >> 16);
}

__device__ __forceinline__ unsigned int cvt_pk_bf16(float lo, float hi) {
  unsigned int r;
  asm("v_cvt_pk_bf16_f32 %0, %1, %2" : "=v"(r) : "v"(lo), "v"(hi));
  return r;
}

__device__ __forceinline__ f32x4 mfma_bf16(u16x8 a, u16x8 b, f32x4 c) {
  return __builtin_amdgcn_mfma_f32_16x16x32_bf16(
      __builtin_bit_cast(bf16x8_t, a), __builtin_bit_cast(bf16x8_t, b), c, 0, 0, 0);
}

// ---------------------------------------------------------------------------
// Kernel 0: prep.  Blocks 0..63: convert Wq*KSCALE and Wv to bf16.
//           Block 64: csk[c] = sum_o Wk[o][c]  (einsum 'oc,bcn->bcn' contracts o)
// ---------------------------------------------------------------------------
__global__ void prep(const float* __restrict__ Wq, const float* __restrict__ Wv,
                     const float* __restrict__ Wk,
                     unsigned short* __restrict__ Qwb, unsigned short* __restrict__ Vwb,
                     float* __restrict__ csk) {
  if (blockIdx.x < 64) {
    const int i = blockIdx.x * 256 + threadIdx.x;     // 0..16383
    Qwb[i] = f2bf(Wq[i] * KSCALE);
    Vwb[i] = f2bf(Wv[i]);
  } else if (threadIdx.x < CC) {
    const int c = threadIdx.x;
    float s = 0.f;
    for (int o = 0; o < CC; ++o) s += Wk[(size_t)o * CC + c];
    csk[c] = s;
  }
}

// ---------------------------------------------------------------------------
// Kernel 1: QKV projection.  Per block: one batch b, 64 pixels.
//  Q[b][n][o] = (Σ_c Wq[o][c]·x[c][n] + bq[o]) * KSCALE   (bf16, pixel-major)
//  K[b][n][c] =  x[c][n]·csk[c] + bk[c]                   (bf16, pixel-major)
//  V[b][o][n] =  Σ_c Wv[o][c]·x[c][n] + bv[o]             (bf16, channel-major)
// ---------------------------------------------------------------------------
__global__ __launch_bounds__(256, 2) void qkv_proj(
    const float* __restrict__ x,
    const unsigned short* __restrict__ Qwb, const float* __restrict__ bq,
    const float* __restrict__ csk, const float* __restrict__ bk,
    const unsigned short* __restrict__ Vwb, const float* __restrict__ bv,
    unsigned short* __restrict__ Q,
    unsigned short* __restrict__ K,
    unsigned short* __restrict__ V)
{
  const int b  = blockIdx.x & 7;            // XCD-friendly: batch = bid % 8
  const int n0 = (blockIdx.x >> 3) << 6;
  const int t  = threadIdx.x;
  const int lane = t & 63;
  const int w  = t >> 6;        // wave 0..3, owns 16 pixel rows
  const int lq = lane & 15;
  const int g  = lane >> 4;

  __shared__ unsigned short xs[64][136];   // [n][c] bf16 x (pad: 2-way banks, 16B align)
  __shared__ unsigned short ks[64][136];   // [n][c] bf16 k
  __shared__ unsigned short vs[128][72];   // V^T staging [c][n]

  // stage x tile -> bf16 LDS (transposed to [n][c]); build K in the same pass
  {
    const int n = t & 63;                  // lane = pixel (coalesced over n)
    const float* xp = x + (size_t)b * (CC * NN) + n0 + n;
    for (int c = t >> 6; c < CC; c += 4) { // c is wave-uniform
      const float xv = xp[(size_t)c * NN];
      xs[n][c] = f2bf(xv);
      ks[n][c] = f2bf(xv * csk[c] + bk[c]);
    }
  }
  __syncthreads();

  // A fragments: A[row=n][k=c]
  u16x8 a[4];
  {
    const unsigned short* ap = &xs[w * 16 + lq][g * 8];
    for (int ksl = 0; ksl < 4; ++ksl) a[ksl] = *(const u16x8*)(ap + ksl * 32);
  }

  for (int ot = 0; ot < 8; ++ot) {
    f32x4 aq = {0.f,0.f,0.f,0.f}, av = {0.f,0.f,0.f,0.f};
    const int o = ot * 16 + lq;            // B-frag col = output channel
    const unsigned short* wq = Qwb + (size_t)o * CC + g * 8;
    const unsigned short* wv = Vwb + (size_t)o * CC + g * 8;
    for (int ksl = 0; ksl < 4; ++ksl) {
      aq = mfma_bf16(a[ksl], *(const u16x8*)(wq + ksl * 32), aq);
      av = mfma_bf16(a[ksl], *(const u16x8*)(wv + ksl * 32), av);
    }
    const float bqv = bq[o] * KSCALE, bvv = bv[o];
    for (int r = 0; r < 4; ++r) {
      const int nl = w * 16 + g * 4 + r;   // D row = local pixel
      Q[((size_t)b * NN + n0 + nl) * CC + o] = f2bf(aq[r] + bqv);
      vs[o][nl] = f2bf(av[r] + bvv);
    }
  }
  __syncthreads();

  // write K pixel-major, coalesced 16B
  {
    unsigned short* kout = K + ((size_t)b * NN + n0) * CC;
    for (int i = t; i < 64 * 16; i += 256) {
      const int n = i >> 4, oc = (i & 15) * 8;
      *(uint4*)(kout + (size_t)n * CC + oc) = *(const uint4*)&ks[n][oc];
    }
  }
  // write V channel-major, coalesced 4B
  {
    unsigned short* vout = V + (size_t)b * (CC * NN) + n0;
    for (int i = t; i < 128 * 32; i += 256) {
      const int c  = i >> 5;
      const int np = (i & 31) << 1;
      *(unsigned int*)(vout + (size_t)c * NN + np) = *(const unsigned int*)&vs[c][np];
    }
  }
}

// ---------------------------------------------------------------------------
// Kernel 2: flash attention + residual.
// Block: batch b (=bid%8, XCD-local KV), 64 q-rows (4 waves x 16). KV tiles 64.
// Double-buffered global_load_lds staging, XOR-swizzled (linear dest,
// pre-swizzled source, swizzled read). 2-phase pipeline, counted vmcnt(8).
// ---------------------------------------------------------------------------
__global__ __launch_bounds__(256, 2) void flash_attn(
    const float* __restrict__ x,
    const unsigned short* __restrict__ Q,
    const unsigned short* __restrict__ K,
    const unsigned short* __restrict__ V,
    float* __restrict__ out)
{
  const int b  = blockIdx.x & 7;
  const int q0 = (blockIdx.x >> 3) << 6;
  const int t  = threadIdx.x;
  const int lane = t & 63;
  const int w  = t >> 6;
  const int lq = lane & 15;
  const int g  = lane >> 4;

  __shared__ unsigned short KtL[2][64 * 128];    // linear [key][c], swizzled content
  __shared__ unsigned short VlL[2][128 * 64];    // linear [c][key], swizzled content
  __shared__ unsigned short Pt[4][16][72];       // per-wave [q][key] (padded)

  // Q fragments (B-operand of swapped QK^T): col q = lane&15
  u16x8 qf[4];
  {
    const unsigned short* qp = Q + ((size_t)b * NN + q0 + w * 16 + lq) * CC + g * 8;
    for (int ksl = 0; ksl < 4; ++ksl) qf[ksl] = *(const u16x8*)(qp + ksl * 32);
  }

  // ---- per-lane loop-invariant staging offsets (pre-swizzled source) ----
  const char* kgb = (const char*)(K + (size_t)b * NN * CC);   // K[b], 256B rows
  const char* vgb = (const char*)(V + (size_t)b * CC * NN);   // V[b], 8192B rows
  const int wq4k = w * 4096;
  int soK[4], soV[4];
  size_t voRow[4];
  #pragma unroll
  for (int j = 0; j < 4; ++j) {
    const int p = wq4k + j * 1024 + lane * 16;
    const int krow = p >> 8;
    soK[j] = (p & ~255) | ((p & 255) ^ ((krow & 7) << 4));
    const int c = p >> 7;
    soV[j] = (p & 127) ^ ((c & 7) << 4);
    voRow[j] = (size_t)c * (NN * 2);
  }

  // ---- swizzled read column offsets (shorts) ----
  const int sw = (lq & 7) << 4;
  int cbk[4], cbv[2];
  #pragma unroll
  for (int ksl = 0; ksl < 4; ++ksl) cbk[ksl] = ((ksl * 64 + g * 16) ^ sw) >> 1;
  #pragma unroll
  for (int kk = 0; kk < 2; ++kk) cbv[kk] = ((kk * 64 + g * 16) ^ sw) >> 1;

  #define STAGE(nb, kv) do {                                                   \
    const char* kg_ = kgb + ((size_t)(kv) << 8);                               \
    const char* vg_ = vgb + ((size_t)(kv) << 1);                               \
    _Pragma("unroll")                                                          \
    for (int j = 0; j < 4; ++j)                                                \
      __builtin_amdgcn_global_load_lds((gu32*)(kg_ + soK[j]),                  \
          (lu32*)((char*)&KtL[nb][0] + wq4k + j * 1024), 16, 0, 0);            \
    _Pragma("unroll")                                                          \
    for (int j = 0; j < 4; ++j)                                                \
      __builtin_amdgcn_global_load_lds((gu32*)(vg_ + voRow[j] + soV[j]),       \
          (lu32*)((char*)&VlL[nb][0] + wq4k + j * 1024), 16, 0, 0);            \
  } while (0)

  f32x4 oacc[8];
  #pragma unroll
  for (int i = 0; i < 8; ++i) oacc[i] = f32x4{0.f, 0.f, 0.f, 0.f};
  float m_run = -1e30f, l_run = 0.f;

  STAGE(0, 0);

  for (int tt = 0; tt < 64; ++tt) {
    const int cur = tt & 1;
    if (tt < 63) {
      STAGE(cur ^ 1, (tt + 1) * 64);
      asm volatile("s_waitcnt vmcnt(8)" ::: "memory");   // tile tt resident, next 8 in flight
    } else {
      asm volatile("s_waitcnt vmcnt(0)" ::: "memory");
    }
    __builtin_amdgcn_s_barrier();

    const unsigned short* kb = KtL[cur];
    const unsigned short* vb = VlL[cur];

    // ---- S^T = K . Q^T  (row = key, col = q) ----
    f32x4 s[4];
    #pragma unroll
    for (int kt = 0; kt < 4; ++kt) s[kt] = f32x4{0.f, 0.f, 0.f, 0.f};
    __builtin_amdgcn_s_setprio(1);
    #pragma unroll
    for (int kt = 0; kt < 4; ++kt) {
      const int rbase = (kt * 16 + lq) * 128;
      #pragma unroll
      for (int ksl = 0; ksl < 4; ++ksl) {
        u16x8 kf = *(const u16x8*)&kb[rbase + cbk[ksl]];
        s[kt] = mfma_bf16(kf, qf[ksl], s[kt]);
      }
    }
    __builtin_amdgcn_s_setprio(0);

    // ---- online softmax (per q column; defer-max threshold 8) ----
    float pm = fmaxf(fmaxf(s[0][0], s[0][1]), fmaxf(s[0][2], s[0][3]));
    #pragma unroll
    for (int kt = 1; kt < 4; ++kt)
      pm = fmaxf(pm, fmaxf(fmaxf(s[kt][0], s[kt][1]), fmaxf(s[kt][2], s[kt][3])));
    pm = fmaxf(pm, __shfl_xor(pm, 16));
    pm = fmaxf(pm, __shfl_xor(pm, 32));
    if (!__all(pm - m_run <= 8.0f)) {
      const float m_new = fmaxf(m_run, pm);
      const float alpha = exp2f(m_run - m_new);
      l_run *= alpha;
      #pragma unroll
      for (int i = 0; i < 8; ++i) {
        oacc[i][0] *= alpha; oacc[i][1] *= alpha;
        oacc[i][2] *= alpha; oacc[i][3] *= alpha;
      }
      m_run = m_new;
    }
    float lsum = 0.f;
    #pragma unroll
    for (int kt = 0; kt < 4; ++kt) {
      const float p0 = exp2f(s[kt][0] - m_run), p1 = exp2f(s[kt][1] - m_run);
      const float p2 = exp2f(s[kt][2] - m_run), p3 = exp2f(s[kt][3] - m_run);
      lsum += (p0 + p1) + (p2 + p3);
      uint2 pw = { cvt_pk_bf16(p0, p1), cvt_pk_bf16(p2, p3) };
      *(uint2*)&Pt[w][lq][kt * 16 + g * 4] = pw;       // keys kt*16 + g*4 + r
    }
    lsum += __shfl_xor(lsum, 16);
    lsum += __shfl_xor(lsum, 32);
    l_run += lsum;
    asm volatile("s_waitcnt lgkmcnt(0)" ::: "memory"); // Pt writes visible to own-wave reads

    // ---- O^T += V^T . P^T  (row = channel, col = q) ----
    __builtin_amdgcn_s_setprio(1);
    #pragma unroll
    for (int kk = 0; kk < 2; ++kk) {
      u16x8 pf = *(const u16x8*)&Pt[w][lq][kk * 32 + g * 8];
      #pragma unroll
      for (int dt = 0; dt < 8; ++dt) {
        u16x8 vf = *(const u16x8*)&vb[(dt * 16 + lq) * 64 + cbv[kk]];
        oacc[dt] = mfma_bf16(vf, pf, oacc[dt]);
      }
    }
    __builtin_amdgcn_s_setprio(0);
    asm volatile("s_waitcnt lgkmcnt(0)" ::: "memory"); // all reads of buf done
    __builtin_amdgcn_s_barrier();                      // safe to overwrite other buf
  }
  #undef STAGE

  // ---- epilogue: normalize, residual, channel-major store ----
  const float rinv = 1.0f / l_run;
  const int n = q0 + w * 16 + lq;
  #pragma unroll
  for (int dt = 0; dt < 8; ++dt) {
    #pragma unroll
    for (int r = 0; r < 4; ++r) {
      const int c = dt * 16 + g * 4 + r;
      const size_t adr = (size_t)b * (CC * NN) + (size_t)c * NN + n;
      out[adr] = x[adr] + oacc[dt][r] * rinv;
    }
  }
}

extern "C" void kernel_launch(void* const* d_in, const int* in_sizes, int n_in,
                              void* d_out, int out_size, void* d_ws, size_t ws_size,
                              hipStream_t stream) {
  (void)in_sizes; (void)n_in; (void)out_size; (void)ws_size;
  const float* x  = (const float*)d_in[0];
  const float* Wq = (const float*)d_in[1];
  const float* bq = (const float*)d_in[2];
  const float* Wk = (const float*)d_in[3];
  const float* bk = (const float*)d_in[4];
  const float* Wv = (const float*)d_in[5];
  const float* bv = (const float*)d_in[6];

  unsigned short* Q   = (unsigned short*)d_ws;               // 8 MB bf16 [B][N][C]
  unsigned short* K   = Q + (size_t)BB * NN * CC;            // 8 MB bf16 [B][N][C]
  unsigned short* V   = K + (size_t)BB * NN * CC;            // 8 MB bf16 [B][C][N]
  unsigned short* Qwb = V + (size_t)BB * NN * CC;            // 32 KB bf16 Wq*scale
  unsigned short* Vwb = Qwb + (size_t)CC * CC;               // 32 KB bf16 Wv
  float* csk = (float*)(Vwb + (size_t)CC * CC);              // 512 B
  float* out = (float*)d_out;

  prep<<<dim3(65), dim3(256), 0, stream>>>(Wq, Wv, Wk, Qwb, Vwb, csk);
  qkv_proj<<<dim3(BB * (NN / 64)), dim3(256), 0, stream>>>(x, Qwb, bq, csk, bk, Vwb, bv, Q, K, V);
  flash_attn<<<dim3(BB * (NN / 64)), dim3(256), 0, stream>>>(x, Q, K, V, out);
}

// Round 5
// 141.586 us; speedup vs baseline: 2.1114x; 1.0389x over previous
//
#include <hip/hip_runtime.h>

#define BB 8
#define CC 128
#define NN 4096   // H*W = 64*64

typedef __bf16 bf16x8_t __attribute__((ext_vector_type(8)));
typedef unsigned short u16x8 __attribute__((ext_vector_type(8)));
typedef float f32x4 __attribute__((ext_vector_type(4)));
typedef __attribute__((address_space(1))) const unsigned int gu32;
typedef __attribute__((address_space(3))) unsigned int lu32;

#define KSCALE 0.12753262456033348f   // (1/sqrt(128)) * log2(e)

__device__ __forceinline__ unsigned short f2bf(float f) {
  unsigned int u = __builtin_bit_cast(unsigned int, f);
  u += 0x7fffu + ((u >> 16) & 1u);          // RNE
  return (unsigned short)(u >> 16);
}

__device__ __forceinline__ unsigned int cvt_pk_bf16(float lo, float hi) {
  unsigned int r;
  asm("v_cvt_pk_bf16_f32 %0, %1, %2" : "=v"(r) : "v"(lo), "v"(hi));
  return r;
}

__device__ __forceinline__ f32x4 mfma_bf16(u16x8 a, u16x8 b, f32x4 c) {
  return __builtin_amdgcn_mfma_f32_16x16x32_bf16(
      __builtin_bit_cast(bf16x8_t, a), __builtin_bit_cast(bf16x8_t, b), c, 0, 0, 0);
}

// ---------------------------------------------------------------------------
// Kernel 0: prep.  Blocks 0..63: convert Wq*KSCALE and Wv to bf16.
//           Block 64: csk[c] = sum_o Wk[o][c]  (einsum 'oc,bcn->bcn' contracts o)
// ---------------------------------------------------------------------------
__global__ void prep(const float* __restrict__ Wq, const float* __restrict__ Wv,
                     const float* __restrict__ Wk,
                     unsigned short* __restrict__ Qwb, unsigned short* __restrict__ Vwb,
                     float* __restrict__ csk) {
  if (blockIdx.x < 64) {
    const int i = blockIdx.x * 256 + threadIdx.x;     // 0..16383
    Qwb[i] = f2bf(Wq[i] * KSCALE);
    Vwb[i] = f2bf(Wv[i]);
  } else if (threadIdx.x < CC) {
    const int c = threadIdx.x;
    float s = 0.f;
    for (int o = 0; o < CC; ++o) s += Wk[(size_t)o * CC + c];
    csk[c] = s;
  }
}

// ---------------------------------------------------------------------------
// Kernel 1: QKV projection.  Per block: one batch b, 64 pixels.
//  Q[b][n][o] = (Σ_c Wq[o][c]·x[c][n] + bq[o]) * KSCALE   (bf16, pixel-major)
//  K[b][n][c] =  x[c][n]·csk[c] + bk[c]                   (bf16, pixel-major)
//  V[b][o][n] =  Σ_c Wv[o][c]·x[c][n] + bv[o]             (bf16, channel-major)
// ---------------------------------------------------------------------------
__global__ __launch_bounds__(256, 2) void qkv_proj(
    const float* __restrict__ x,
    const unsigned short* __restrict__ Qwb, const float* __restrict__ bq,
    const float* __restrict__ csk, const float* __restrict__ bk,
    const unsigned short* __restrict__ Vwb, const float* __restrict__ bv,
    unsigned short* __restrict__ Q,
    unsigned short* __restrict__ K,
    unsigned short* __restrict__ V)
{
  const int b  = blockIdx.x & 7;            // XCD-friendly: batch = bid % 8
  const int n0 = (blockIdx.x >> 3) << 6;
  const int t  = threadIdx.x;
  const int lane = t & 63;
  const int w  = t >> 6;        // wave 0..3, owns 16 pixel rows
  const int lq = lane & 15;
  const int g  = lane >> 4;

  __shared__ unsigned short xs[64][136];   // [n][c] bf16 x (pad: 2-way banks, 16B align)
  __shared__ unsigned short ks[64][136];   // [n][c] bf16 k
  __shared__ unsigned short vs[128][72];   // V^T staging [c][n]

  // stage x tile -> bf16 LDS (transposed to [n][c]); build K in the same pass
  {
    const int n = t & 63;                  // lane = pixel (coalesced over n)
    const float* xp = x + (size_t)b * (CC * NN) + n0 + n;
    for (int c = t >> 6; c < CC; c += 4) { // c is wave-uniform
      const float xv = xp[(size_t)c * NN];
      xs[n][c] = f2bf(xv);
      ks[n][c] = f2bf(xv * csk[c] + bk[c]);
    }
  }
  __syncthreads();

  // A fragments: A[row=n][k=c]
  u16x8 a[4];
  {
    const unsigned short* ap = &xs[w * 16 + lq][g * 8];
    for (int ksl = 0; ksl < 4; ++ksl) a[ksl] = *(const u16x8*)(ap + ksl * 32);
  }

  for (int ot = 0; ot < 8; ++ot) {
    f32x4 aq = {0.f,0.f,0.f,0.f}, av = {0.f,0.f,0.f,0.f};
    const int o = ot * 16 + lq;            // B-frag col = output channel
    const unsigned short* wq = Qwb + (size_t)o * CC + g * 8;
    const unsigned short* wv = Vwb + (size_t)o * CC + g * 8;
    for (int ksl = 0; ksl < 4; ++ksl) {
      aq = mfma_bf16(a[ksl], *(const u16x8*)(wq + ksl * 32), aq);
      av = mfma_bf16(a[ksl], *(const u16x8*)(wv + ksl * 32), av);
    }
    const float bqv = bq[o] * KSCALE, bvv = bv[o];
    for (int r = 0; r < 4; ++r) {
      const int nl = w * 16 + g * 4 + r;   // D row = local pixel
      Q[((size_t)b * NN + n0 + nl) * CC + o] = f2bf(aq[r] + bqv);
      vs[o][nl] = f2bf(av[r] + bvv);
    }
  }
  __syncthreads();

  // write K pixel-major, coalesced 16B
  {
    unsigned short* kout = K + ((size_t)b * NN + n0) * CC;
    for (int i = t; i < 64 * 16; i += 256) {
      const int n = i >> 4, oc = (i & 15) * 8;
      *(uint4*)(kout + (size_t)n * CC + oc) = *(const uint4*)&ks[n][oc];
    }
  }
  // write V channel-major, coalesced 4B
  {
    unsigned short* vout = V + (size_t)b * (CC * NN) + n0;
    for (int i = t; i < 128 * 32; i += 256) {
      const int c  = i >> 5;
      const int np = (i & 31) << 1;
      *(unsigned int*)(vout + (size_t)c * NN + np) = *(const unsigned int*)&vs[c][np];
    }
  }
}

// ---------------------------------------------------------------------------
// Kernel 2: flash attention partials, KV split 2-way.
// Block: batch b (=bid%8), 128 q-rows (8 waves x 16), half of KV (2048 keys).
// Emits unnormalized O (fp32, channel-major) + per-row (m,l).
// LDS: KV double-buffered (64KB) + swizzled Pt (16KB) = 80KB -> 2 blocks/CU.
// ---------------------------------------------------------------------------
__global__ __launch_bounds__(512, 4) void flash_attn(
    const unsigned short* __restrict__ Q,
    const unsigned short* __restrict__ K,
    const unsigned short* __restrict__ V,
    float* __restrict__ PO0, float* __restrict__ PO1,
    float2* __restrict__ PML)
{
  const int bid = blockIdx.x;
  const int b  = bid & 7;
  const int q0 = ((bid >> 3) & 31) << 7;     // 128 q-rows per block
  const int sp = bid >> 8;                   // KV half 0/1
  const int kv0 = sp << 11;                  // 2048 keys per half
  const int t  = threadIdx.x;
  const int lane = t & 63;
  const int w  = t >> 6;                     // wave 0..7
  const int lq = lane & 15;
  const int g  = lane >> 4;
  const int swb = (lq & 7) << 4;             // XOR swizzle (byte bit4)

  __shared__ unsigned short KtL[2][64 * 128];   // [key][c] swizzled, 16KB each
  __shared__ unsigned short VlL[2][128 * 64];   // [c][key] swizzled, 16KB each
  __shared__ unsigned short Pt[8][16 * 64];     // per-wave [q][key], swizzled

  // Q fragments (B-operand of swapped QK^T): col q = lane&15
  u16x8 qf[4];
  {
    const unsigned short* qp = Q + ((size_t)b * NN + q0 + w * 16 + lq) * CC + g * 8;
    #pragma unroll
    for (int ksl = 0; ksl < 4; ++ksl) qf[ksl] = *(const u16x8*)(qp + ksl * 32);
  }

  // ---- staging offsets: 512 threads x 16B x 2 rounds per 16KB tile ----
  const char* kgb = (const char*)(K + (size_t)b * NN * CC);   // 256B rows
  const char* vgb = (const char*)(V + (size_t)b * CC * NN);   // 8192B rows
  int soK[2], soV[2], voRow[2];
  #pragma unroll
  for (int j = 0; j < 2; ++j) {
    const int p = t * 16 + j * 8192;
    const int krow = p >> 8;
    soK[j] = (p & ~255) | ((p & 255) ^ ((krow & 7) << 4));
    const int c = p >> 7;
    soV[j] = (p & 127) ^ ((c & 7) << 4);
    voRow[j] = c * (NN * 2);
  }
  const int p0 = t * 16;

  #define STAGE(nb, kv) do {                                                   \
    const char* kg_ = kgb + ((size_t)(kv) << 8);                               \
    const char* vg_ = vgb + ((size_t)(kv) << 1);                               \
    _Pragma("unroll")                                                          \
    for (int j = 0; j < 2; ++j)                                                \
      __builtin_amdgcn_global_load_lds((gu32*)(kg_ + soK[j]),                  \
          (lu32*)((char*)&KtL[nb][0] + p0 + j * 8192), 16, 0, 0);              \
    _Pragma("unroll")                                                          \
    for (int j = 0; j < 2; ++j)                                                \
      __builtin_amdgcn_global_load_lds((gu32*)(vg_ + voRow[j] + soV[j]),       \
          (lu32*)((char*)&VlL[nb][0] + p0 + j * 8192), 16, 0, 0);              \
  } while (0)

  f32x4 oacc[8];
  #pragma unroll
  for (int i = 0; i < 8; ++i) oacc[i] = f32x4{0.f, 0.f, 0.f, 0.f};
  float m_run = -1e30f, l_run = 0.f;

  // read-column byte offsets (swizzled)
  int cbkB[4];
  #pragma unroll
  for (int ksl = 0; ksl < 4; ++ksl) cbkB[ksl] = (ksl * 64 + g * 16) ^ swb;

  STAGE(0, kv0);

  for (int tt = 0; tt < 32; ++tt) {
    const int cur = tt & 1;
    if (tt < 31) {
      STAGE(cur ^ 1, kv0 + (tt + 1) * 64);
      asm volatile("s_waitcnt vmcnt(4)" ::: "memory");   // this tile resident, next in flight
    } else {
      asm volatile("s_waitcnt vmcnt(0)" ::: "memory");
    }
    __builtin_amdgcn_s_barrier();

    const char* kb = (const char*)&KtL[cur][0];
    const char* vb = (const char*)&VlL[cur][0];

    // ---- S^T = K . Q^T  (row = key, col = q) ----
    f32x4 s[4];
    #pragma unroll
    for (int kt = 0; kt < 4; ++kt) s[kt] = f32x4{0.f, 0.f, 0.f, 0.f};
    __builtin_amdgcn_s_setprio(1);
    #pragma unroll
    for (int kt = 0; kt < 4; ++kt) {
      const char* kp = kb + (kt * 16 + lq) * 256;
      #pragma unroll
      for (int ksl = 0; ksl < 4; ++ksl) {
        u16x8 kf = *(const u16x8*)(kp + cbkB[ksl]);
        s[kt] = mfma_bf16(kf, qf[ksl], s[kt]);
      }
    }
    __builtin_amdgcn_s_setprio(0);

    // ---- online softmax (per q column; defer-max threshold 8) ----
    float pm = fmaxf(fmaxf(s[0][0], s[0][1]), fmaxf(s[0][2], s[0][3]));
    #pragma unroll
    for (int kt = 1; kt < 4; ++kt)
      pm = fmaxf(pm, fmaxf(fmaxf(s[kt][0], s[kt][1]), fmaxf(s[kt][2], s[kt][3])));
    pm = fmaxf(pm, __shfl_xor(pm, 16));
    pm = fmaxf(pm, __shfl_xor(pm, 32));
    if (!__all(pm - m_run <= 8.0f)) {
      const float m_new = fmaxf(m_run, pm);
      const float alpha = exp2f(m_run - m_new);
      l_run *= alpha;
      #pragma unroll
      for (int i = 0; i < 8; ++i) {
        oacc[i][0] *= alpha; oacc[i][1] *= alpha;
        oacc[i][2] *= alpha; oacc[i][3] *= alpha;
      }
      m_run = m_new;
    }
    float lsum = 0.f;
    char* ptw = (char*)&Pt[w][0] + lq * 128;
    #pragma unroll
    for (int kt = 0; kt < 4; ++kt) {
      const float e0 = exp2f(s[kt][0] - m_run), e1 = exp2f(s[kt][1] - m_run);
      const float e2 = exp2f(s[kt][2] - m_run), e3 = exp2f(s[kt][3] - m_run);
      lsum += (e0 + e1) + (e2 + e3);
      uint2 pw = { cvt_pk_bf16(e0, e1), cvt_pk_bf16(e2, e3) };
      *(uint2*)(ptw + ((kt * 32 + g * 8) ^ swb)) = pw;   // keys kt*16+g*4+r
    }
    lsum += __shfl_xor(lsum, 16);
    lsum += __shfl_xor(lsum, 32);
    l_run += lsum;
    asm volatile("s_waitcnt lgkmcnt(0)" ::: "memory"); // Pt writes visible to own-wave reads

    // ---- O^T += V^T . P^T  (row = channel, col = q) ----
    __builtin_amdgcn_s_setprio(1);
    #pragma unroll
    for (int kk = 0; kk < 2; ++kk) {
      u16x8 pf = *(const u16x8*)(ptw + ((kk * 64 + g * 16) ^ swb));
      const char* vp = vb + ((kk * 64 + g * 16) ^ swb);
      #pragma unroll
      for (int dt = 0; dt < 8; ++dt) {
        u16x8 vf = *(const u16x8*)(vp + (dt * 16 + lq) * 128);
        oacc[dt] = mfma_bf16(vf, pf, oacc[dt]);
      }
    }
    __builtin_amdgcn_s_setprio(0);
    asm volatile("s_waitcnt lgkmcnt(0)" ::: "memory"); // all reads of buf done
    __builtin_amdgcn_s_barrier();                      // safe to overwrite other buf
  }
  #undef STAGE

  // ---- epilogue: unnormalized fp32 partials, channel-major + (m,l) ----
  float* po = (sp ? PO1 : PO0) + (size_t)b * (CC * NN);
  const int n = q0 + w * 16 + lq;
  #pragma unroll
  for (int dt = 0; dt < 8; ++dt) {
    #pragma unroll
    for (int r = 0; r < 4; ++r) {
      const int c = dt * 16 + g * 4 + r;
      po[(size_t)c * NN + n] = oacc[dt][r];
    }
  }
  if (g == 0) PML[((size_t)sp * BB + b) * NN + n] = float2{m_run, l_run};
}

// ---------------------------------------------------------------------------
// Kernel 3: combine two KV-half partials + residual.
// out = x + (w0*O0 + w1*O1) / (w0*l0 + w1*l1),  w_s = exp2(m_s - max(m0,m1))
// ---------------------------------------------------------------------------
__global__ __launch_bounds__(256) void combine(
    const float* __restrict__ x, const float* __restrict__ PO1,
    const float2* __restrict__ PML, float* __restrict__ out)
{
  const size_t base = ((size_t)blockIdx.x * 256 + threadIdx.x) * 4;
  const int n = (int)(base & 4095);
  const int rest = (int)(base >> 12);
  const int b = rest >> 7;                    // rest = b*128 + c
  const float2* ml0 = PML + (size_t)b * NN + n;
  const float2* ml1 = PML + (size_t)(BB + b) * NN + n;
  float4 o0 = *(const float4*)(out + base);   // half 0 stored in d_out
  float4 o1 = *(const float4*)(PO1 + base);
  float4 xv = *(const float4*)(x + base);
  float4 r;
  #pragma unroll
  for (int i = 0; i < 4; ++i) {
    const float m0 = ml0[i].x, l0 = ml0[i].y;
    const float m1 = ml1[i].x, l1 = ml1[i].y;
    const float M = fmaxf(m0, m1);
    const float w0 = exp2f(m0 - M), w1 = exp2f(m1 - M);
    const float num = w0 * ((const float*)&o0)[i] + w1 * ((const float*)&o1)[i];
    const float den = w0 * l0 + w1 * l1;
    ((float*)&r)[i] = ((const float*)&xv)[i] + num / den;
  }
  *(float4*)(out + base) = r;
}

extern "C" void kernel_launch(void* const* d_in, const int* in_sizes, int n_in,
                              void* d_out, int out_size, void* d_ws, size_t ws_size,
                              hipStream_t stream) {
  (void)in_sizes; (void)n_in; (void)out_size; (void)ws_size;
  const float* x  = (const float*)d_in[0];
  const float* Wq = (const float*)d_in[1];
  const float* bq = (const float*)d_in[2];
  const float* Wk = (const float*)d_in[3];
  const float* bk = (const float*)d_in[4];
  const float* Wv = (const float*)d_in[5];
  const float* bv = (const float*)d_in[6];

  unsigned short* Q   = (unsigned short*)d_ws;               // 8 MB bf16 [B][N][C]
  unsigned short* K   = Q + (size_t)BB * NN * CC;            // 8 MB bf16 [B][N][C]
  unsigned short* V   = K + (size_t)BB * NN * CC;            // 8 MB bf16 [B][C][N]
  float* PO1          = (float*)(V + (size_t)BB * NN * CC);  // 16 MB fp32 partial (half 1)
  float2* PML         = (float2*)(PO1 + (size_t)BB * CC * NN); // 512 KB stats
  unsigned short* Qwb = (unsigned short*)(PML + (size_t)2 * BB * NN); // 32 KB
  unsigned short* Vwb = Qwb + (size_t)CC * CC;               // 32 KB
  float* csk = (float*)(Vwb + (size_t)CC * CC);              // 512 B
  float* out = (float*)d_out;                                // also partial half 0

  prep<<<dim3(65), dim3(256), 0, stream>>>(Wq, Wv, Wk, Qwb, Vwb, csk);
  qkv_proj<<<dim3(BB * (NN / 64)), dim3(256), 0, stream>>>(x, Qwb, bq, csk, bk, Vwb, bv, Q, K, V);
  flash_attn<<<dim3(BB * 32 * 2), dim3(512), 0, stream>>>(Q, K, V, out, PO1, PML);
  combine<<<dim3((BB * CC * NN) / (256 * 4)), dim3(256), 0, stream>>>(x, PO1, PML, out);
}